// Round 2
// 508.576 us; speedup vs baseline: 1.0426x; 1.0426x over previous
//
#include <hip/hip_runtime.h>
#include <math.h>

typedef __bf16 bf16x8 __attribute__((ext_vector_type(8)));
typedef float f32x4 __attribute__((ext_vector_type(4)));
typedef unsigned short ushort_t;
typedef unsigned int uint_t;

#define BB 16
#define SS 4096
#define DDIM 512
#define NCODE 256
#define MTOK 65536

// d_out layout (floats)
#define LOSS_OFF 33554432
#define IDX_OFF  33554433
#define WGT_OFF  33619969

// d_ws layout (floats)
#define WS_LOSS 0      // lu at 0, lk at 64 (separate cache lines)
#define WS_LOG  128    // 32 (logit pairs per b)
#define WS_WGT  192    // 32
#define WS_POOL 256    // 8192
#define WS_C2   8448   // 256
#define WS_RSTD 8704   // 512
#define WS_BAR  9216   // grid-barrier counter (1 word) -> total 9217

__device__ __forceinline__ void async16(void* lds, const void* gptr) {
  __builtin_amdgcn_global_load_lds(
      (const __attribute__((address_space(1))) unsigned int*)(gptr),
      (__attribute__((address_space(3))) unsigned int*)(lds),
      16, 0, 0);
}

__global__ void init_ws(const float* __restrict__ stds, float* ws) {
  int i = blockIdx.x * blockDim.x + threadIdx.x;
  if (i < 8704) ws[i] = 0.f;
  else if (i < 9216) ws[WS_RSTD + (i - 8704)] = 1.f / stds[i - 8704];
  else if (i == 9216) ws[i] = 0.f;  // barrier counter
}

// per-code |c|^2 + fp32->bf16 hi/lo planes in K-tiled, bank-swizzled layout.
// Tile kb (32 k): slot = code*4 + (chunk ^ ((code>>1)&3)), chunk = (k%32)/8.
// hi plane: cbt[kb*1024 + slot]; lo plane at +16384 slots. (total 512 KB)
__global__ __launch_bounds__(64) void c2_convert(
    const float* __restrict__ cb, float* __restrict__ c2,
    bf16x8* __restrict__ cbt) {
  const int k = blockIdx.x, t = threadIdx.x;
  const float4* row = (const float4*)(cb + (size_t)k * DDIM);
  float4 a = row[t * 2], b = row[t * 2 + 1];
  float v[8] = {a.x, a.y, a.z, a.w, b.x, b.y, b.z, b.w};
  bf16x8 hi, lo;
  float s = 0.f;
  #pragma unroll
  for (int j = 0; j < 8; j++) {
    s = fmaf(v[j], v[j], s);
    __bf16 hh = (__bf16)v[j];
    hi[j] = hh;
    lo[j] = (__bf16)(v[j] - (float)hh);
  }
  const int kb = t >> 2, q = t & 3;
  const int slot = k * 4 + (q ^ ((k >> 1) & 3));
  cbt[kb * 1024 + slot] = hi;
  cbt[16384 + kb * 1024 + slot] = lo;
  for (int m = 1; m <= 32; m <<= 1) s += __shfl_xor(s, m, 64);
  if (t == 0) c2[k] = s;
}

__global__ __launch_bounds__(512) void pool_kernel(const float* __restrict__ x,
                                                   float* __restrict__ pool) {
  int b = blockIdx.x, sc = blockIdx.y, d = threadIdx.x;
  const float* p = x + ((size_t)b * SS + (size_t)sc * 256) * DDIM + d;
  float s = 0.f;
  #pragma unroll 8
  for (int i = 0; i < 256; i++) s += p[(size_t)i * DDIM];
  atomicAdd(&pool[b * DDIM + d], s);
}

__global__ __launch_bounds__(256) void selector_partial(
    const float* __restrict__ poolsum, const float* __restrict__ w1,
    const float* __restrict__ b1, const float* __restrict__ w2,
    float* __restrict__ logits) {
  const int b = blockIdx.x, hc = blockIdx.y;
  const int t = threadIdx.x, h = t & 31, ds = t >> 5;
  const int hu = hc * 32 + h;
  float sum = 0.f;
  for (int i = 0; i < 64; i++) {
    int d = ds * 64 + i;
    sum = fmaf(poolsum[b * DDIM + d] * (1.f / SS), w1[d * 256 + hu], sum);
  }
  __shared__ float red[8][32];
  red[ds][h] = sum;
  __syncthreads();
  if (t < 32) {
    float tot = 0.f;
    #pragma unroll
    for (int j = 0; j < 8; j++) tot += red[j][t];
    int hu2 = hc * 32 + t;
    float hv = fmaxf(tot + b1[hu2], 0.f);
    atomicAdd(&logits[b * 2 + 0], hv * w2[hu2 * 2]);
    atomicAdd(&logits[b * 2 + 1], hv * w2[hu2 * 2 + 1]);
  }
}

__global__ void selector_final(const float* __restrict__ logits,
                               const float* __restrict__ b2,
                               float* __restrict__ wgt, float* __restrict__ out) {
  int b = threadIdx.x;
  if (b >= BB) return;
  float l0 = logits[b * 2] + b2[0], l1 = logits[b * 2 + 1] + b2[1];
  float mx = fmaxf(l0, l1);
  float e0 = expf(l0 - mx), e1 = expf(l1 - mx);
  float inv = 1.f / (e0 + e1);
  wgt[b * 2] = e0 * inv; wgt[b * 2 + 1] = e1 * inv;
  out[WGT_OFF + b * 2] = e0 * inv; out[WGT_OFF + b * 2 + 1] = e1 * inv;
}

// all-blocks-resident grid barrier (512 blocks = 2/CU x 256 CU, guaranteed by
// __launch_bounds__(256,2) + 49.7KB LDS). Device-scope atomics (cross-XCD safe).
__device__ __forceinline__ void grid_barrier(uint_t* cnt, uint_t nb) {
  __syncthreads();
  if (threadIdx.x == 0) {
    __hip_atomic_fetch_add(cnt, 1u, __ATOMIC_ACQ_REL, __HIP_MEMORY_SCOPE_AGENT);
    while (__hip_atomic_load(cnt, __ATOMIC_ACQUIRE, __HIP_MEMORY_SCOPE_AGENT) < nb)
      __builtin_amdgcn_s_sleep(2);
  }
  __syncthreads();
}

// fused: split-bf16 MFMA GEMM (128 tokens x 256 codes) -> per-token top-4 ->
// grid barrier (cbt scratch in d_out is done being read) -> exact fp32 rescore
// + fused elementwise output + loss, all in one kernel. x re-read and cb
// gathers in the epilogue are L2/MALL-hot; out stores are nontemporal.
__global__ __launch_bounds__(256, 2) void gemm_fused(
    const float* __restrict__ x, const ushort_t* __restrict__ cbt,
    const float* __restrict__ means, const float* __restrict__ stds,
    const float* __restrict__ rstd, const float* __restrict__ cbf,
    const float* __restrict__ c2g, const float* __restrict__ wsel,
    float* __restrict__ out, float* __restrict__ idxout,
    float* __restrict__ loss_acc, uint_t* __restrict__ bar) {
  __shared__ bf16x8 Ahi[512], Alo[512], Bhi[1024], Blo[1024];
  __shared__ uint_t stash[4][32];
  __shared__ float slu[4], slk[4];
  const int tid = threadIdx.x;
  const int lane = tid & 63, w = tid >> 6;
  const size_t token0 = (size_t)blockIdx.x * 128;
  const int c = lane & 15, quad = lane >> 4;

  f32x4 acc[2][16];
  #pragma unroll
  for (int tt = 0; tt < 2; tt++)
    #pragma unroll
    for (int ct = 0; ct < 16; ct++) {
      f32x4 z = {0.f, 0.f, 0.f, 0.f};
      acc[tt][ct] = z;
    }

  const int r = tid >> 1, h = tid & 1;
  const float* xrow = x + (token0 + r) * DDIM;

  for (int kbi = 0; kbi < 16; kbi++) {
    const int kb = kbi * 32;
    __syncthreads();
    // B staging: contiguous async16 (global slot order == LDS slot order)
    #pragma unroll
    for (int i = 0; i < 4; i++) {
      const int slot = i * 256 + tid;
      async16((void*)&Bhi[slot], (const void*)(cbt + ((size_t)kbi * 1024 + slot) * 8));
      async16((void*)&Blo[slot], (const void*)(cbt + ((size_t)(16384 + kbi * 1024) + slot) * 8));
    }
    // A staging: fp32 load -> normalize (rstd mul) -> bf16 hi/lo -> ds_write_b128
    #pragma unroll
    for (int sub = 0; sub < 2; sub++) {
      const int q = h * 2 + sub;
      const int kk = kb + q * 8;
      float4 xa = *(const float4*)(xrow + kk);
      float4 xb = *(const float4*)(xrow + kk + 4);
      float4 ma = *(const float4*)(means + kk);
      float4 mb = *(const float4*)(means + kk + 4);
      float4 ra = *(const float4*)(rstd + kk);
      float4 rb = *(const float4*)(rstd + kk + 4);
      float xv[8] = {xa.x, xa.y, xa.z, xa.w, xb.x, xb.y, xb.z, xb.w};
      float mv[8] = {ma.x, ma.y, ma.z, ma.w, mb.x, mb.y, mb.z, mb.w};
      float rv[8] = {ra.x, ra.y, ra.z, ra.w, rb.x, rb.y, rb.z, rb.w};
      bf16x8 hi, lo;
      #pragma unroll
      for (int j = 0; j < 8; j++) {
        float xn = (xv[j] - mv[j]) * rv[j];
        __bf16 hh = (__bf16)xn;
        hi[j] = hh;
        lo[j] = (__bf16)(xn - (float)hh);
      }
      const int p = (q + (r >> 1)) & 3;
      Ahi[r * 4 + p] = hi;
      Alo[r * 4 + p] = lo;
    }
    __syncthreads();

    bf16x8 ahi[2], alo[2];
    #pragma unroll
    for (int tt = 0; tt < 2; tt++) {
      const int rr = w * 32 + tt * 16 + c;
      const int p = (quad + (rr >> 1)) & 3;
      ahi[tt] = Ahi[rr * 4 + p];
      alo[tt] = Alo[rr * 4 + p];
    }
    #pragma unroll
    for (int ct = 0; ct < 16; ct++) {
      const int cf = ct * 16 + c;
      const int slot = cf * 4 + (quad ^ ((cf >> 1) & 3));
      bf16x8 bhi = Bhi[slot];
      bf16x8 blo = Blo[slot];
      #pragma unroll
      for (int tt = 0; tt < 2; tt++) {
        acc[tt][ct] = __builtin_amdgcn_mfma_f32_16x16x32_bf16(ahi[tt], bhi, acc[tt][ct], 0, 0, 0);
        acc[tt][ct] = __builtin_amdgcn_mfma_f32_16x16x32_bf16(ahi[tt], blo, acc[tt][ct], 0, 0, 0);
        acc[tt][ct] = __builtin_amdgcn_mfma_f32_16x16x32_bf16(alo[tt], bhi, acc[tt][ct], 0, 0, 0);
      }
    }
  }

  // top-4 per token over 256 codes (score = c2 - 2*dot; x2 cancels)
  float c2v[16];
  #pragma unroll
  for (int ct = 0; ct < 16; ct++) c2v[ct] = c2g[ct * 16 + c];

#define LESS(av, ai, bv, bi) ((av) < (bv) || ((av) == (bv) && (ai) < (bi)))
#define INS4(v, i)                                                            \
  if (LESS(v, i, tv3, ti3)) {                                                 \
    tv3 = (v); ti3 = (i);                                                     \
    if (LESS(tv3, ti3, tv2, ti2)) { float tf = tv2; int tj = ti2; tv2 = tv3; ti2 = ti3; tv3 = tf; ti3 = tj; } \
    if (LESS(tv2, ti2, tv1, ti1)) { float tf = tv1; int tj = ti1; tv1 = tv2; ti1 = ti2; tv2 = tf; ti2 = tj; } \
    if (LESS(tv1, ti1, tv0, ti0)) { float tf = tv0; int tj = ti0; tv0 = tv1; ti0 = ti1; tv1 = tf; ti1 = tj; } \
  }

  #pragma unroll
  for (int tt = 0; tt < 2; tt++) {
    #pragma unroll
    for (int reg = 0; reg < 4; reg++) {
      float tv0 = 3.4e38f, tv1 = 3.4e38f, tv2 = 3.4e38f, tv3 = 3.4e38f;
      int ti0 = 0, ti1 = 0, ti2 = 0, ti3 = 0;
      #pragma unroll
      for (int ct = 0; ct < 16; ct++) {
        float vv = fmaf(-2.f, acc[tt][ct][reg], c2v[ct]);
        int ii = ct * 16 + c;
        INS4(vv, ii);
      }
      #pragma unroll
      for (int m = 1; m <= 8; m <<= 1) {
        float ov0 = __shfl_xor(tv0, m, 64), ov1 = __shfl_xor(tv1, m, 64);
        float ov2 = __shfl_xor(tv2, m, 64), ov3 = __shfl_xor(tv3, m, 64);
        int oi0 = __shfl_xor(ti0, m, 64), oi1 = __shfl_xor(ti1, m, 64);
        int oi2 = __shfl_xor(ti2, m, 64), oi3 = __shfl_xor(ti3, m, 64);
        INS4(ov0, oi0); INS4(ov1, oi1); INS4(ov2, oi2); INS4(ov3, oi3);
      }
      if (c == 0) {
        uint_t packed = (uint_t)ti0 | ((uint_t)ti1 << 8) |
                        ((uint_t)ti2 << 16) | ((uint_t)ti3 << 24);
        stash[w][tt * 16 + quad * 4 + reg] = packed;
      }
    }
  }
#undef INS4
#undef LESS

  // WAR fence: first 512KB of `out` still holds cbt planes other blocks read.
  grid_barrier(bar, (uint_t)gridDim.x);

  // ---- exact fp32 rescore of 4 candidates + fused elementwise output ----
  const int dA = lane * 4;
  const int dB = 256 + lane * 4;
  float4 mA = *(const float4*)(means + dA), mB = *(const float4*)(means + dB);
  float4 sA = *(const float4*)(stds + dA),  sB = *(const float4*)(stds + dB);
  const float step = (float)(2.0 / 7.0);
  const int b = (int)(token0 >> 12);
  const float w0 = wsel[b * 2], w1v = wsel[b * 2 + 1];
  float lu = 0.f, lk = 0.f;

  #pragma unroll 2
  for (int it = 0; it < 32; it++) {
    const size_t token = token0 + (size_t)w * 32 + it;
    const uint_t packed = stash[w][it];
    int k0 = (int)(packed & 255), k1 = (int)((packed >> 8) & 255);
    int k2 = (int)((packed >> 16) & 255), k3 = (int)((packed >> 24) & 255);
    const float* xr = x + token * DDIM;
    float4 xA = *(const float4*)(xr + dA);
    float4 xB = *(const float4*)(xr + dB);
    float xnA0 = __fdiv_rn(xA.x - mA.x, sA.x), xnA1 = __fdiv_rn(xA.y - mA.y, sA.y);
    float xnA2 = __fdiv_rn(xA.z - mA.z, sA.z), xnA3 = __fdiv_rn(xA.w - mA.w, sA.w);
    float xnB0 = __fdiv_rn(xB.x - mB.x, sB.x), xnB1 = __fdiv_rn(xB.y - mB.y, sB.y);
    float xnB2 = __fdiv_rn(xB.z - mB.z, sB.z), xnB3 = __fdiv_rn(xB.w - mB.w, sB.w);

    float4 cA[4], cB[4];
    float dot[4];
    int kc[4] = {k0, k1, k2, k3};
    #pragma unroll
    for (int j = 0; j < 4; j++) {
      const float* cr = cbf + (size_t)kc[j] * DDIM;
      cA[j] = *(const float4*)(cr + dA);
      cB[j] = *(const float4*)(cr + dB);
      float dj = xnA0 * cA[j].x + xnA1 * cA[j].y + xnA2 * cA[j].z + xnA3 * cA[j].w +
                 xnB0 * cB[j].x + xnB1 * cB[j].y + xnB2 * cB[j].z + xnB3 * cB[j].w;
      for (int m = 1; m <= 32; m <<= 1) dj += __shfl_xor(dj, m, 64);
      dot[j] = dj;
    }
    float bd = fmaf(-2.f, dot[0], c2g[k0]);
    int bj = 0, bk = k0;
    #pragma unroll
    for (int j = 1; j < 4; j++) {
      float dj = fmaf(-2.f, dot[j], c2g[kc[j]]);
      if (dj < bd || (dj == bd && kc[j] < bk)) { bd = dj; bj = j; bk = kc[j]; }
    }
    if (lane == 0) idxout[token] = (float)bk;

    float4 cwA, cwB;
    cwA = (bj == 0) ? cA[0] : (bj == 1) ? cA[1] : (bj == 2) ? cA[2] : cA[3];
    cwB = (bj == 0) ? cB[0] : (bj == 1) ? cB[1] : (bj == 2) ? cB[2] : cB[3];

    float4 oA, oB;
#define DOE(xx, cw, mm, ss, dst)                                              \
    { float xc = fminf(fmaxf(xx, -1.f), 1.f);                                 \
      float fi = rintf(__fdiv_rn(xc + 1.f, step));                            \
      float qq = __fadd_rn(__fmul_rn(fi, step), -1.f);                        \
      float qk = __fadd_rn(__fmul_rn(cw, ss), mm);                            \
      float qu_ = xx + (qq - xx);                                             \
      float qks = xx + (qk - xx);                                             \
      dst = w0 * qu_ + w1v * qks;                                             \
      float du = xx - qq; lu = fmaf(du, du, lu);                              \
      float dk = xx - qk; lk = fmaf(dk, dk, lk); }
    DOE(xA.x, cwA.x, mA.x, sA.x, oA.x)
    DOE(xA.y, cwA.y, mA.y, sA.y, oA.y)
    DOE(xA.z, cwA.z, mA.z, sA.z, oA.z)
    DOE(xA.w, cwA.w, mA.w, sA.w, oA.w)
    DOE(xB.x, cwB.x, mB.x, sB.x, oB.x)
    DOE(xB.y, cwB.y, mB.y, sB.y, oB.y)
    DOE(xB.z, cwB.z, mB.z, sB.z, oB.z)
    DOE(xB.w, cwB.w, mB.w, sB.w, oB.w)
#undef DOE
    f32x4 voA = {oA.x, oA.y, oA.z, oA.w};
    f32x4 voB = {oB.x, oB.y, oB.z, oB.w};
    __builtin_nontemporal_store(voA, (f32x4*)(out + token * DDIM + dA));
    __builtin_nontemporal_store(voB, (f32x4*)(out + token * DDIM + dB));
  }

  for (int m = 1; m <= 32; m <<= 1) {
    lu += __shfl_xor(lu, m, 64);
    lk += __shfl_xor(lk, m, 64);
  }
  if (lane == 0) { slu[w] = lu; slk[w] = lk; }
  __syncthreads();
  if (tid == 0) {
    atomicAdd(loss_acc + 0, slu[0] + slu[1] + slu[2] + slu[3]);
    atomicAdd(loss_acc + 64, slk[0] + slk[1] + slk[2] + slk[3]);
  }
}

__global__ void finalize_kernel(const float* __restrict__ ls, float* __restrict__ out_loss) {
  const float invN = 1.f / ((float)MTOK * (float)DDIM);
  out_loss[0] = 0.25f * (ls[0] * invN) + 0.25f * (ls[64] * invN);
}

extern "C" void kernel_launch(void* const* d_in, const int* in_sizes, int n_in,
                              void* d_out, int out_size, void* d_ws, size_t ws_size,
                              hipStream_t stream) {
  const float* x     = (const float*)d_in[0];
  const float* cbf   = (const float*)d_in[1];
  const float* means = (const float*)d_in[2];
  const float* stds  = (const float*)d_in[3];
  const float* w1    = (const float*)d_in[4];
  const float* b1    = (const float*)d_in[5];
  const float* w2    = (const float*)d_in[6];
  const float* b2    = (const float*)d_in[7];
  float* out = (float*)d_out;
  float* ws  = (float*)d_ws;
  bf16x8* cbt = (bf16x8*)d_out;  // tiled bf16 planes in d_out scratch (overwritten post-barrier)

  hipLaunchKernelGGL(init_ws, dim3(37), dim3(256), 0, stream, stds, ws);
  hipLaunchKernelGGL(c2_convert, dim3(NCODE), dim3(64), 0, stream, cbf, ws + WS_C2, cbt);
  hipLaunchKernelGGL(pool_kernel, dim3(BB, 16), dim3(512), 0, stream, x, ws + WS_POOL);
  hipLaunchKernelGGL(selector_partial, dim3(BB, 8), dim3(256), 0, stream,
                     ws + WS_POOL, w1, b1, w2, ws + WS_LOG);
  hipLaunchKernelGGL(selector_final, dim3(1), dim3(16), 0, stream,
                     ws + WS_LOG, b2, ws + WS_WGT, out);
  hipLaunchKernelGGL(gemm_fused, dim3(MTOK / 128), dim3(256), 0, stream,
                     x, (const ushort_t*)d_out, means, stds, ws + WS_RSTD, cbf,
                     ws + WS_C2, ws + WS_WGT, out, out + IDX_OFF, ws + WS_LOSS,
                     (uint_t*)(ws + WS_BAR));
  hipLaunchKernelGGL(finalize_kernel, dim3(1), dim3(1), 0, stream,
                     ws + WS_LOSS, out + LOSS_OFF);
}

// Round 3
// 386.822 us; speedup vs baseline: 1.3708x; 1.3148x over previous
//
#include <hip/hip_runtime.h>
#include <math.h>

typedef __bf16 bf16x8 __attribute__((ext_vector_type(8)));
typedef float f32x4 __attribute__((ext_vector_type(4)));
typedef unsigned short ushort_t;
typedef unsigned int uint_t;

#define BB 16
#define SS 4096
#define DDIM 512
#define NCODE 256
#define MTOK 65536

// d_out layout (floats)
#define LOSS_OFF 33554432
#define IDX_OFF  33554433
#define WGT_OFF  33619969

// d_ws layout (floats)
#define WS_LOSS 0      // lu at 0, lk at 64 (separate cache lines)
#define WS_LOG  128    // 32 (unused now, kept for layout stability)
#define WS_WGT  192    // 32
#define WS_POOL 256    // 8192
#define WS_C2   8448   // 256
#define WS_RSTD 8704   // 512
#define WS_BAR  9216   // grid-barrier counter (1 word) -> total 9217

__device__ __forceinline__ void async16(void* lds, const void* gptr) {
  __builtin_amdgcn_global_load_lds(
      (const __attribute__((address_space(1))) unsigned int*)(gptr),
      (__attribute__((address_space(3))) unsigned int*)(lds),
      16, 0, 0);
}

__global__ void init_ws(const float* __restrict__ stds, float* ws) {
  int i = blockIdx.x * blockDim.x + threadIdx.x;
  if (i < 8704) ws[i] = 0.f;
  else if (i < 9216) ws[WS_RSTD + (i - 8704)] = 1.f / stds[i - 8704];
  else if (i == 9216) ws[i] = 0.f;  // barrier counter
}

// per-code |c|^2 + fp32->bf16 hi/lo planes in K-tiled, bank-swizzled layout.
// Tile kb (32 k): slot = code*4 + (chunk ^ ((code>>1)&3)), chunk = (k%32)/8.
// hi plane: cbt[kb*1024 + slot]; lo plane at +16384 slots. (total 512 KB)
__global__ __launch_bounds__(64) void c2_convert(
    const float* __restrict__ cb, float* __restrict__ c2,
    bf16x8* __restrict__ cbt) {
  const int k = blockIdx.x, t = threadIdx.x;
  const float4* row = (const float4*)(cb + (size_t)k * DDIM);
  float4 a = row[t * 2], b = row[t * 2 + 1];
  float v[8] = {a.x, a.y, a.z, a.w, b.x, b.y, b.z, b.w};
  bf16x8 hi, lo;
  float s = 0.f;
  #pragma unroll
  for (int j = 0; j < 8; j++) {
    s = fmaf(v[j], v[j], s);
    __bf16 hh = (__bf16)v[j];
    hi[j] = hh;
    lo[j] = (__bf16)(v[j] - (float)hh);
  }
  const int kb = t >> 2, q = t & 3;
  const int slot = k * 4 + (q ^ ((k >> 1) & 3));
  cbt[kb * 1024 + slot] = hi;
  cbt[16384 + kb * 1024 + slot] = lo;
  for (int m = 1; m <= 32; m <<= 1) s += __shfl_xor(s, m, 64);
  if (t == 0) c2[k] = s;
}

__global__ __launch_bounds__(512) void pool_kernel(const float* __restrict__ x,
                                                   float* __restrict__ pool) {
  int b = blockIdx.x, sc = blockIdx.y, d = threadIdx.x;
  const float* p = x + ((size_t)b * SS + (size_t)sc * 256) * DDIM + d;
  float s = 0.f;
  #pragma unroll 8
  for (int i = 0; i < 256; i++) s += p[(size_t)i * DDIM];
  atomicAdd(&pool[b * DDIM + d], s);
}

// one block per batch: hidden layer + logits + softmax, no atomics.
__global__ __launch_bounds__(256) void selector(
    const float* __restrict__ poolsum, const float* __restrict__ w1,
    const float* __restrict__ b1, const float* __restrict__ w2,
    const float* __restrict__ b2, float* __restrict__ wgt,
    float* __restrict__ out) {
  const int b = blockIdx.x, t = threadIdx.x;
  __shared__ float pl[512];
  pl[t] = poolsum[b * DDIM + t] * (1.f / SS);
  pl[t + 256] = poolsum[b * DDIM + 256 + t] * (1.f / SS);
  __syncthreads();
  float acc = 0.f;
  #pragma unroll 8
  for (int d = 0; d < DDIM; d++) acc = fmaf(pl[d], w1[d * 256 + t], acc);
  float hv = fmaxf(acc + b1[t], 0.f);
  float p0 = hv * w2[t * 2], p1 = hv * w2[t * 2 + 1];
  #pragma unroll
  for (int m = 1; m <= 32; m <<= 1) {
    p0 += __shfl_xor(p0, m, 64);
    p1 += __shfl_xor(p1, m, 64);
  }
  __shared__ float r0[4], r1[4];
  const int w = t >> 6;
  if ((t & 63) == 0) { r0[w] = p0; r1[w] = p1; }
  __syncthreads();
  if (t == 0) {
    float l0 = r0[0] + r0[1] + r0[2] + r0[3] + b2[0];
    float l1 = r1[0] + r1[1] + r1[2] + r1[3] + b2[1];
    float mx = fmaxf(l0, l1);
    float e0 = expf(l0 - mx), e1 = expf(l1 - mx);
    float inv = 1.f / (e0 + e1);
    wgt[b * 2] = e0 * inv; wgt[b * 2 + 1] = e1 * inv;
    out[WGT_OFF + b * 2] = e0 * inv; out[WGT_OFF + b * 2 + 1] = e1 * inv;
  }
}

// all-blocks-resident grid barrier (512 blocks = 2/CU x 256 CU, guaranteed by
// __launch_bounds__(256,2) + ~49.7KB LDS). Device-scope atomics (cross-XCD safe).
__device__ __forceinline__ void grid_barrier(uint_t* cnt, uint_t nb) {
  __syncthreads();
  if (threadIdx.x == 0) {
    __hip_atomic_fetch_add(cnt, 1u, __ATOMIC_ACQ_REL, __HIP_MEMORY_SCOPE_AGENT);
    while (__hip_atomic_load(cnt, __ATOMIC_ACQUIRE, __HIP_MEMORY_SCOPE_AGENT) < nb)
      __builtin_amdgcn_s_sleep(2);
  }
  __syncthreads();
}

// fused: split-bf16 MFMA GEMM (128 tokens x 256 codes) -> per-token top-2 ->
// grid barrier (cbt scratch in d_out is done being read) -> exact fp32 rescore
// of 2 candidates + fused elementwise output + loss. NT stores for out.
__global__ __launch_bounds__(256, 2) void gemm_fused(
    const float* __restrict__ x, const ushort_t* __restrict__ cbt,
    const float* __restrict__ means, const float* __restrict__ stds,
    const float* __restrict__ rstd, const float* __restrict__ cbf,
    const float* __restrict__ c2g, const float* __restrict__ wsel,
    float* __restrict__ out, float* __restrict__ idxout,
    float* __restrict__ loss_acc, uint_t* __restrict__ bar) {
  __shared__ bf16x8 Ahi[512], Alo[512], Bhi[1024], Blo[1024];
  __shared__ uint_t stash[4][32];
  __shared__ float slu[4], slk[4];
  const int tid = threadIdx.x;
  const int lane = tid & 63, w = tid >> 6;
  const size_t token0 = (size_t)blockIdx.x * 128;
  const int c = lane & 15, quad = lane >> 4;

  f32x4 acc[2][16];
  #pragma unroll
  for (int tt = 0; tt < 2; tt++)
    #pragma unroll
    for (int ct = 0; ct < 16; ct++) {
      f32x4 z = {0.f, 0.f, 0.f, 0.f};
      acc[tt][ct] = z;
    }

  const int r = tid >> 1, h = tid & 1;
  const float* xrow = x + (token0 + r) * DDIM;

  for (int kbi = 0; kbi < 16; kbi++) {
    const int kb = kbi * 32;
    __syncthreads();
    // B staging: contiguous async16 (global slot order == LDS slot order)
    #pragma unroll
    for (int i = 0; i < 4; i++) {
      const int slot = i * 256 + tid;
      async16((void*)&Bhi[slot], (const void*)(cbt + ((size_t)kbi * 1024 + slot) * 8));
      async16((void*)&Blo[slot], (const void*)(cbt + ((size_t)(16384 + kbi * 1024) + slot) * 8));
    }
    // A staging: fp32 load -> normalize (rstd mul) -> bf16 hi/lo -> ds_write_b128
    #pragma unroll
    for (int sub = 0; sub < 2; sub++) {
      const int q = h * 2 + sub;
      const int kk = kb + q * 8;
      float4 xa = *(const float4*)(xrow + kk);
      float4 xb = *(const float4*)(xrow + kk + 4);
      float4 ma = *(const float4*)(means + kk);
      float4 mb = *(const float4*)(means + kk + 4);
      float4 ra = *(const float4*)(rstd + kk);
      float4 rb = *(const float4*)(rstd + kk + 4);
      float xv[8] = {xa.x, xa.y, xa.z, xa.w, xb.x, xb.y, xb.z, xb.w};
      float mv[8] = {ma.x, ma.y, ma.z, ma.w, mb.x, mb.y, mb.z, mb.w};
      float rv[8] = {ra.x, ra.y, ra.z, ra.w, rb.x, rb.y, rb.z, rb.w};
      bf16x8 hi, lo;
      #pragma unroll
      for (int j = 0; j < 8; j++) {
        float xn = (xv[j] - mv[j]) * rv[j];
        __bf16 hh = (__bf16)xn;
        hi[j] = hh;
        lo[j] = (__bf16)(xn - (float)hh);
      }
      const int p = (q + (r >> 1)) & 3;
      Ahi[r * 4 + p] = hi;
      Alo[r * 4 + p] = lo;
    }
    __syncthreads();

    bf16x8 ahi[2], alo[2];
    #pragma unroll
    for (int tt = 0; tt < 2; tt++) {
      const int rr = w * 32 + tt * 16 + c;
      const int p = (quad + (rr >> 1)) & 3;
      ahi[tt] = Ahi[rr * 4 + p];
      alo[tt] = Alo[rr * 4 + p];
    }
    #pragma unroll
    for (int ct = 0; ct < 16; ct++) {
      const int cf = ct * 16 + c;
      const int slot = cf * 4 + (quad ^ ((cf >> 1) & 3));
      bf16x8 bhi = Bhi[slot];
      bf16x8 blo = Blo[slot];
      #pragma unroll
      for (int tt = 0; tt < 2; tt++) {
        acc[tt][ct] = __builtin_amdgcn_mfma_f32_16x16x32_bf16(ahi[tt], bhi, acc[tt][ct], 0, 0, 0);
        acc[tt][ct] = __builtin_amdgcn_mfma_f32_16x16x32_bf16(ahi[tt], blo, acc[tt][ct], 0, 0, 0);
        acc[tt][ct] = __builtin_amdgcn_mfma_f32_16x16x32_bf16(alo[tt], bhi, acc[tt][ct], 0, 0, 0);
      }
    }
  }

  // top-2 per token over 256 codes (score = c2 - 2*dot; x2 cancels).
  // 3-term split-bf16 score error ~3e-3 abs; true argmin in top-2 unless two
  // other codes sit within ~6e-3 of the min (P ~ 5e-8/token).
  float c2v[16];
  #pragma unroll
  for (int ct = 0; ct < 16; ct++) c2v[ct] = c2g[ct * 16 + c];

#define LESS(av, ai, bv, bi) ((av) < (bv) || ((av) == (bv) && (ai) < (bi)))
#define INS2(v, i)                                                            \
  if (LESS(v, i, tv1, ti1)) {                                                 \
    tv1 = (v); ti1 = (i);                                                     \
    if (LESS(tv1, ti1, tv0, ti0)) { float tf = tv0; int tj = ti0; tv0 = tv1; ti0 = ti1; tv1 = tf; ti1 = tj; } \
  }

  #pragma unroll
  for (int tt = 0; tt < 2; tt++) {
    #pragma unroll
    for (int reg = 0; reg < 4; reg++) {
      float tv0 = 3.4e38f, tv1 = 3.4e38f;
      int ti0 = 0, ti1 = 0;
      #pragma unroll
      for (int ct = 0; ct < 16; ct++) {
        float vv = fmaf(-2.f, acc[tt][ct][reg], c2v[ct]);
        int ii = ct * 16 + c;
        INS2(vv, ii);
      }
      #pragma unroll
      for (int m = 1; m <= 8; m <<= 1) {
        float ov0 = __shfl_xor(tv0, m, 64), ov1 = __shfl_xor(tv1, m, 64);
        int oi0 = __shfl_xor(ti0, m, 64), oi1 = __shfl_xor(ti1, m, 64);
        INS2(ov0, oi0); INS2(ov1, oi1);
      }
      if (c == 0)
        stash[w][tt * 16 + quad * 4 + reg] = (uint_t)ti0 | ((uint_t)ti1 << 16);
    }
  }
#undef INS2
#undef LESS

  // WAR fence: first 512KB of `out` still holds cbt planes other blocks read.
  grid_barrier(bar, (uint_t)gridDim.x);

  // ---- exact fp32 rescore of 2 candidates + fused elementwise output ----
  const int dA = lane * 4;
  const int dB = 256 + lane * 4;
  float4 mA = *(const float4*)(means + dA), mB = *(const float4*)(means + dB);
  float4 sA = *(const float4*)(stds + dA),  sB = *(const float4*)(stds + dB);
  float4 rA = *(const float4*)(rstd + dA),  rB = *(const float4*)(rstd + dB);
  const float step = (float)(2.0 / 7.0);
  const int b = (int)(token0 >> 12);
  const float w0 = wsel[b * 2], w1v = wsel[b * 2 + 1];
  float lu = 0.f, lk = 0.f;

  #pragma unroll 2
  for (int it = 0; it < 32; it++) {
    const size_t token = token0 + (size_t)w * 32 + it;
    const uint_t packed = stash[w][it];
    const int k0 = (int)(packed & 0xffffu), k1 = (int)(packed >> 16);
    const float* xr = x + token * DDIM;
    float4 xA = *(const float4*)(xr + dA);
    float4 xB = *(const float4*)(xr + dB);
    const float* c0 = cbf + (size_t)k0 * DDIM;
    const float* c1 = cbf + (size_t)k1 * DDIM;
    float4 cA0 = *(const float4*)(c0 + dA), cB0 = *(const float4*)(c0 + dB);
    float4 cA1 = *(const float4*)(c1 + dA), cB1 = *(const float4*)(c1 + dB);

    float xnA0 = (xA.x - mA.x) * rA.x, xnA1 = (xA.y - mA.y) * rA.y;
    float xnA2 = (xA.z - mA.z) * rA.z, xnA3 = (xA.w - mA.w) * rA.w;
    float xnB0 = (xB.x - mB.x) * rB.x, xnB1 = (xB.y - mB.y) * rB.y;
    float xnB2 = (xB.z - mB.z) * rB.z, xnB3 = (xB.w - mB.w) * rB.w;

    float d0 = xnA0 * cA0.x + xnA1 * cA0.y + xnA2 * cA0.z + xnA3 * cA0.w +
               xnB0 * cB0.x + xnB1 * cB0.y + xnB2 * cB0.z + xnB3 * cB0.w;
    float d1 = xnA0 * cA1.x + xnA1 * cA1.y + xnA2 * cA1.z + xnA3 * cA1.w +
               xnB0 * cB1.x + xnB1 * cB1.y + xnB2 * cB1.z + xnB3 * cB1.w;
    #pragma unroll
    for (int m = 1; m <= 32; m <<= 1) {
      d0 += __shfl_xor(d0, m, 64);
      d1 += __shfl_xor(d1, m, 64);
    }
    float s0 = fmaf(-2.f, d0, c2g[k0]);
    float s1 = fmaf(-2.f, d1, c2g[k1]);
    const bool take1 = (s1 < s0) || (s1 == s0 && k1 < k0);
    const int bk = take1 ? k1 : k0;
    if (lane == 0) idxout[token] = (float)bk;
    float4 cwA, cwB;
    cwA = take1 ? cA1 : cA0;
    cwB = take1 ? cB1 : cB0;

    float4 oA, oB;
#define DOE(xx, cw, mm, ss, dst)                                              \
    { float xc = fminf(fmaxf(xx, -1.f), 1.f);                                 \
      float fi = rintf(__fdiv_rn(xc + 1.f, step));                            \
      float qq = __fadd_rn(__fmul_rn(fi, step), -1.f);                        \
      float qk = __fadd_rn(__fmul_rn(cw, ss), mm);                            \
      float qu_ = xx + (qq - xx);                                             \
      float qks = xx + (qk - xx);                                             \
      dst = w0 * qu_ + w1v * qks;                                             \
      float du = xx - qq; lu = fmaf(du, du, lu);                              \
      float dk = xx - qk; lk = fmaf(dk, dk, lk); }
    DOE(xA.x, cwA.x, mA.x, sA.x, oA.x)
    DOE(xA.y, cwA.y, mA.y, sA.y, oA.y)
    DOE(xA.z, cwA.z, mA.z, sA.z, oA.z)
    DOE(xA.w, cwA.w, mA.w, sA.w, oA.w)
    DOE(xB.x, cwB.x, mB.x, sB.x, oB.x)
    DOE(xB.y, cwB.y, mB.y, sB.y, oB.y)
    DOE(xB.z, cwB.z, mB.z, sB.z, oB.z)
    DOE(xB.w, cwB.w, mB.w, sB.w, oB.w)
#undef DOE
    f32x4 voA = {oA.x, oA.y, oA.z, oA.w};
    f32x4 voB = {oB.x, oB.y, oB.z, oB.w};
    __builtin_nontemporal_store(voA, (f32x4*)(out + token * DDIM + dA));
    __builtin_nontemporal_store(voB, (f32x4*)(out + token * DDIM + dB));
  }

  for (int m = 1; m <= 32; m <<= 1) {
    lu += __shfl_xor(lu, m, 64);
    lk += __shfl_xor(lk, m, 64);
  }
  if (lane == 0) { slu[w] = lu; slk[w] = lk; }
  __syncthreads();
  if (tid == 0) {
    atomicAdd(loss_acc + 0, slu[0] + slu[1] + slu[2] + slu[3]);
    atomicAdd(loss_acc + 64, slk[0] + slk[1] + slk[2] + slk[3]);
  }
}

__global__ void finalize_kernel(const float* __restrict__ ls, float* __restrict__ out_loss) {
  const float invN = 1.f / ((float)MTOK * (float)DDIM);
  out_loss[0] = 0.25f * (ls[0] * invN) + 0.25f * (ls[64] * invN);
}

extern "C" void kernel_launch(void* const* d_in, const int* in_sizes, int n_in,
                              void* d_out, int out_size, void* d_ws, size_t ws_size,
                              hipStream_t stream) {
  const float* x     = (const float*)d_in[0];
  const float* cbf   = (const float*)d_in[1];
  const float* means = (const float*)d_in[2];
  const float* stds  = (const float*)d_in[3];
  const float* w1    = (const float*)d_in[4];
  const float* b1    = (const float*)d_in[5];
  const float* w2    = (const float*)d_in[6];
  const float* b2    = (const float*)d_in[7];
  float* out = (float*)d_out;
  float* ws  = (float*)d_ws;
  bf16x8* cbt = (bf16x8*)d_out;  // tiled bf16 planes in d_out scratch (overwritten post-barrier)

  hipLaunchKernelGGL(init_ws, dim3(37), dim3(256), 0, stream, stds, ws);
  hipLaunchKernelGGL(c2_convert, dim3(NCODE), dim3(64), 0, stream, cbf, ws + WS_C2, cbt);
  hipLaunchKernelGGL(pool_kernel, dim3(BB, 16), dim3(512), 0, stream, x, ws + WS_POOL);
  hipLaunchKernelGGL(selector, dim3(BB), dim3(256), 0, stream,
                     ws + WS_POOL, w1, b1, w2, b2, ws + WS_WGT, out);
  hipLaunchKernelGGL(gemm_fused, dim3(MTOK / 128), dim3(256), 0, stream,
                     x, (const ushort_t*)d_out, means, stds, ws + WS_RSTD, cbf,
                     ws + WS_C2, ws + WS_WGT, out, out + IDX_OFF, ws + WS_LOSS,
                     (uint_t*)(ws + WS_BAR));
  hipLaunchKernelGGL(finalize_kernel, dim3(1), dim3(1), 0, stream,
                     ws + WS_LOSS, out + LOSS_OFF);
}